// Round 3
// baseline (940.649 us; speedup 1.0000x reference)
//
#include <hip/hip_runtime.h>

// SelfAttentionBlock channel-attention, MI355X fp16-MFMA pipeline.
// N=32, C=512, A=256, H=W=64 (P=4096 flat spatial, PP=1024 pooled).

typedef _Float16 half8 __attribute__((ext_vector_type(8)));
typedef _Float16 half4v __attribute__((ext_vector_type(4)));
typedef float f32x4 __attribute__((ext_vector_type(4)));

#define NB 32
#define CD 512
#define AD 256
#define PD 4096
#define PPD 1024

// ---------------- workspace layout (bytes) ----------------
#define OFF_XT    0UL
#define OFF_WC    134217728UL
#define OFF_THETA 134742016UL
#define OFF_GT    168296448UL
#define OFF_PHI   235405312UL
#define OFF_ATTN  252182528UL

__global__ __launch_bounds__(256) void k_prep_w(const float* __restrict__ w_g,
                                                const float* __restrict__ w_phi,
                                                _Float16* __restrict__ Wc) {
    int idx4 = blockIdx.x * 256 + threadIdx.x;
    int flat = idx4 * 4;
    const float* src = (flat < AD * CD) ? (w_g + flat) : (w_phi + (flat - AD * CD));
    float4 v = *(const float4*)src;
    half4v h;
    h[0] = (_Float16)v.x; h[1] = (_Float16)v.y; h[2] = (_Float16)v.z; h[3] = (_Float16)v.w;
    *(half4v*)(Wc + flat) = h;
}

// Read x fp32 tile (32 c x 128 p), produce xT fp16 (transposed) + theta (pooled).
__global__ __launch_bounds__(256) void k_prep_x(const float* __restrict__ x,
                                                _Float16* __restrict__ xT,
                                                _Float16* __restrict__ theta) {
    __shared__ _Float16 tile[32 * 136];
    int pb = blockIdx.x;
    int cb = blockIdx.y;
    int n  = blockIdx.z;
    int t  = threadIdx.x;
    int p0 = pb * 128, c0 = cb * 32;

    const float* xbase = x + ((size_t)n * CD + c0) * PD + p0;
#pragma unroll
    for (int i = 0; i < 4; ++i) {
        int idx = i * 256 + t;
        int cl = idx >> 5;
        int ch = idx & 31;
        float4 v = *(const float4*)(xbase + (size_t)cl * PD + ch * 4);
        half4v h;
        h[0] = (_Float16)v.x; h[1] = (_Float16)v.y; h[2] = (_Float16)v.z; h[3] = (_Float16)v.w;
        *(half4v*)&tile[cl * 136 + ch * 4] = h;
    }
    __syncthreads();

    {
        int pl = t >> 1, ch = t & 1;
        _Float16 vals[16] __attribute__((aligned(16)));
#pragma unroll
        for (int j = 0; j < 16; ++j) vals[j] = tile[(ch * 16 + j) * 136 + pl];
        _Float16* dst = xT + ((size_t)n * PD + p0 + pl) * CD + c0 + ch * 16;
        *(uint4*)dst       = *(uint4*)&vals[0];
        *(uint4*)(dst + 8) = *(uint4*)&vals[8];
    }
    {
        int cl = t >> 3, u0 = (t & 7) * 4;
        _Float16 o[4] __attribute__((aligned(8)));
#pragma unroll
        for (int j = 0; j < 4; ++j) {
            int w2 = (u0 + j) * 2;
            float a0 = (float)tile[cl * 136 + w2];
            float a1 = (float)tile[cl * 136 + w2 + 1];
            float a2 = (float)tile[cl * 136 + 64 + w2];
            float a3 = (float)tile[cl * 136 + 64 + w2 + 1];
            o[j] = (_Float16)fmaxf(fmaxf(a0, a1), fmaxf(a2, a3));
        }
        _Float16* dst = theta + ((size_t)n * CD + c0 + cl) * PPD + pb * 32 + u0;
        *(uint2*)dst = *(uint2*)&o[0];
    }
}

// GEMM1: D[a][p] = sum_c Wc[a][c] * x[c][p], 128x128 tile, K=512.
// Direct global->fragment K-loop (Wc + xT tiles are L2-resident; no LDS staging,
// no barriers). LDS used only for the epilogue transpose/pool.
__global__ __launch_bounds__(256) void k_gemm1(const _Float16* __restrict__ Wc,
                                               const _Float16* __restrict__ xT,
                                               const float* __restrict__ b_g,
                                               const float* __restrict__ b_phi,
                                               _Float16* __restrict__ gT,
                                               _Float16* __restrict__ phi) {
    __shared__ _Float16 T[128 * 136];   // epilogue only (34816 B)

    int pb = blockIdx.x, ab = blockIdx.y, n = blockIdx.z;
    int a0 = ab * 128, p0 = pb * 128;
    int t = threadIdx.x;
    int w = t >> 6, l = t & 63;
    int ln = l & 15, q = l >> 4;
    int mw = (w >> 1) * 64, nw = (w & 1) * 64;

    const f32x4 vzero = {0.f, 0.f, 0.f, 0.f};
    f32x4 acc[4][4];
#pragma unroll
    for (int i = 0; i < 4; ++i)
#pragma unroll
        for (int j = 0; j < 4; ++j) acc[i][j] = vzero;

    // per-lane fragment row pointers (same addresses the LDS reads used)
    const _Float16* arow[4];
    const _Float16* brow[4];
#pragma unroll
    for (int mt = 0; mt < 4; ++mt)
        arow[mt] = Wc + (size_t)(a0 + mw + mt * 16 + ln) * CD + q * 8;
#pragma unroll
    for (int nt = 0; nt < 4; ++nt)
        brow[nt] = xT + ((size_t)n * PD + p0 + nw + nt * 16 + ln) * CD + q * 8;

#pragma unroll 4
    for (int ks = 0; ks < 16; ++ks) {
        half8 af[4], bf[4];
#pragma unroll
        for (int mt = 0; mt < 4; ++mt) af[mt] = *(const half8*)(arow[mt] + ks * 32);
#pragma unroll
        for (int nt = 0; nt < 4; ++nt) bf[nt] = *(const half8*)(brow[nt] + ks * 32);
#pragma unroll
        for (int mt = 0; mt < 4; ++mt)
#pragma unroll
            for (int nt = 0; nt < 4; ++nt)
                acc[mt][nt] = __builtin_amdgcn_mfma_f32_16x16x32_f16(af[mt], bf[nt], acc[mt][nt], 0, 0, 0);
    }

    bool is_g = (a0 < 256);
    const float* bias = is_g ? b_g : b_phi;
    int abase = a0 - (is_g ? 0 : 256);
    float bv[4][4];
#pragma unroll
    for (int mt = 0; mt < 4; ++mt)
#pragma unroll
        for (int r = 0; r < 4; ++r) bv[mt][r] = bias[abase + mw + mt * 16 + q * 4 + r];

    if (is_g) {
#pragma unroll
        for (int mt = 0; mt < 4; ++mt)
#pragma unroll
            for (int nt = 0; nt < 4; ++nt)
#pragma unroll
                for (int r = 0; r < 4; ++r) {
                    int al = mw + mt * 16 + q * 4 + r;
                    int pl = nw + nt * 16 + ln;
                    T[pl * 136 + al] = (_Float16)(acc[mt][nt][r] + bv[mt][r]);
                }
        __syncthreads();
#pragma unroll
        for (int i = 0; i < 8; ++i) {
            int idx = i * 256 + t;
            int pl = idx >> 4, ch = idx & 15;
            uint4 v = *(uint4*)&T[pl * 136 + ch * 8];
            *(uint4*)(gT + ((size_t)n * PD + p0 + pl) * AD + a0 + ch * 8) = v;
        }
    } else {
#pragma unroll
        for (int mt = 0; mt < 4; ++mt)
#pragma unroll
            for (int nt = 0; nt < 4; ++nt)
#pragma unroll
                for (int r = 0; r < 4; ++r) {
                    int al = mw + mt * 16 + q * 4 + r;
                    int pl = nw + nt * 16 + ln;
                    T[al * 136 + pl] = (_Float16)(acc[mt][nt][r] + bv[mt][r]);
                }
        __syncthreads();
        int al = t >> 1, hf = t & 1;
        _Float16 o[16] __attribute__((aligned(16)));
#pragma unroll
        for (int j = 0; j < 16; ++j) {
            int u = hf * 16 + j;
            float v0 = (float)T[al * 136 + 2 * u];
            float v1 = (float)T[al * 136 + 2 * u + 1];
            float v2 = (float)T[al * 136 + 64 + 2 * u];
            float v3 = (float)T[al * 136 + 64 + 2 * u + 1];
            o[j] = (_Float16)fmaxf(fmaxf(v0, v1), fmaxf(v2, v3));
        }
        _Float16* dst = phi + ((size_t)n * AD + (a0 - 256) + al) * PPD + pb * 32 + hf * 16;
        *(uint4*)dst       = *(uint4*)&o[0];
        *(uint4*)(dst + 8) = *(uint4*)&o[8];
    }
}

// GEMM2 + softmax, K-split across waves for occupancy.
__global__ __launch_bounds__(256) void k_gemm2(const _Float16* __restrict__ theta,
                                               const _Float16* __restrict__ phi,
                                               _Float16* __restrict__ attn) {
    __shared__ float red[3 * 64 * 65];
    int cb = blockIdx.x;   // 0..31
    int n  = blockIdx.y;
    int t = threadIdx.x, w = t >> 6, l = t & 63;
    int ln = l & 15, q = l >> 4;
    int c0 = cb * 16;

    const _Float16* Ab = theta + ((size_t)n * CD + c0 + ln) * PPD + w * 256;
    const _Float16* Bb = phi + ((size_t)n * AD + ln) * PPD + w * 256;

    const f32x4 vzero = {0.f, 0.f, 0.f, 0.f};
    f32x4 acc[16];
#pragma unroll
    for (int i = 0; i < 16; ++i) acc[i] = vzero;

    for (int k0 = 0; k0 < 256; k0 += 32) {
        half8 af = *(const half8*)(Ab + k0 + q * 8);
#pragma unroll
        for (int nt = 0; nt < 16; ++nt) {
            half8 bf = *(const half8*)(Bb + (size_t)nt * 16 * PPD + k0 + q * 8);
            acc[nt] = __builtin_amdgcn_mfma_f32_16x16x32_f16(af, bf, acc[nt], 0, 0, 0);
        }
    }

    if (w > 0) {
        float* dst = red + (w - 1) * 64 * 65 + l * 65;
#pragma unroll
        for (int nt = 0; nt < 16; ++nt)
#pragma unroll
            for (int r = 0; r < 4; ++r) dst[nt * 4 + r] = acc[nt][r];
    }
    __syncthreads();
    if (w == 0) {
#pragma unroll
        for (int j = 0; j < 3; ++j) {
            const float* src = red + j * 64 * 65 + l * 65;
#pragma unroll
            for (int nt = 0; nt < 16; ++nt)
#pragma unroll
                for (int r = 0; r < 4; ++r) acc[nt][r] += src[nt * 4 + r];
        }
#pragma unroll
        for (int r = 0; r < 4; ++r) {
            float m = -1e30f;
#pragma unroll
            for (int nt = 0; nt < 16; ++nt) m = fmaxf(m, acc[nt][r]);
#pragma unroll
            for (int s = 1; s < 16; s <<= 1) m = fmaxf(m, __shfl_xor(m, s, 64));
            float sum = 0.f;
#pragma unroll
            for (int nt = 0; nt < 16; ++nt) {
                float e = __expf(acc[nt][r] - m);
                acc[nt][r] = e;
                sum += e;
            }
#pragma unroll
            for (int s = 1; s < 16; s <<= 1) sum += __shfl_xor(sum, s, 64);
            float inv = 1.0f / sum;
            int c = c0 + q * 4 + r;
            _Float16* dst = attn + ((size_t)n * CD + c) * AD + ln;
#pragma unroll
            for (int nt = 0; nt < 16; ++nt) dst[nt * 16] = (_Float16)(acc[nt][r] * inv);
        }
    }
}

// GEMM3: out[c][p] = sum_a attn[c][a] * gT[p][a] + x[c][p].  128x128 tile, K=256.
// Operand-swapped (D[p][c] -> float4 epilogue). Direct global->fragment K-loop:
// gT tile (64 KB, shared by 4 cb-blocks on same XCD) and attn (256 KB/n) are
// L2-resident, so no LDS, no barriers; occupancy is VGPR-bound only.
__global__ __launch_bounds__(256) void k_gemm3(const _Float16* __restrict__ attn,
                                               const _Float16* __restrict__ gT,
                                               const float* __restrict__ x,
                                               float* __restrict__ out) {
    int pb = blockIdx.x, cb = blockIdx.y, n = blockIdx.z;
    int c0 = cb * 128, p0 = pb * 128;
    int t = threadIdx.x;
    int w = t >> 6, l = t & 63;
    int ln = l & 15, q = l >> 4;
    int mw = (w >> 1) * 64, nw = (w & 1) * 64;   // mw: p-tile, nw: c-tile

    const f32x4 vzero = {0.f, 0.f, 0.f, 0.f};
    f32x4 acc[4][4];
#pragma unroll
    for (int i = 0; i < 4; ++i)
#pragma unroll
        for (int j = 0; j < 4; ++j) acc[i][j] = vzero;

    // A-operand = gT rows (p dim) -> D rows = p; B-operand = attn rows (c dim) -> D cols = c
    const _Float16* arow[4];
    const _Float16* brow[4];
#pragma unroll
    for (int mt = 0; mt < 4; ++mt)
        arow[mt] = gT + ((size_t)n * PD + p0 + mw + mt * 16 + ln) * AD + q * 8;
#pragma unroll
    for (int nt = 0; nt < 4; ++nt)
        brow[nt] = attn + ((size_t)n * CD + c0 + nw + nt * 16 + ln) * AD + q * 8;

#pragma unroll 4
    for (int ks = 0; ks < 8; ++ks) {
        half8 af[4], bf[4];
#pragma unroll
        for (int mt = 0; mt < 4; ++mt) af[mt] = *(const half8*)(arow[mt] + ks * 32);
#pragma unroll
        for (int nt = 0; nt < 4; ++nt) bf[nt] = *(const half8*)(brow[nt] + ks * 32);
#pragma unroll
        for (int mt = 0; mt < 4; ++mt)
#pragma unroll
            for (int nt = 0; nt < 4; ++nt)
                acc[mt][nt] = __builtin_amdgcn_mfma_f32_16x16x32_f16(af[mt], bf[nt], acc[mt][nt], 0, 0, 0);
    }

    // epilogue: lane (q,ln) of tile (mt,nt) holds p = p0+mw+mt*16+q*4..+3, c = c0+nw+nt*16+ln
#pragma unroll
    for (int mt = 0; mt < 4; ++mt) {
        int p = p0 + mw + mt * 16 + q * 4;
#pragma unroll
        for (int nt = 0; nt < 4; ++nt) {
            int c = c0 + nw + nt * 16 + ln;
            size_t off = ((size_t)n * CD + c) * PD + p;
            f32x4 xv = *(const f32x4*)(x + off);
            *(f32x4*)(out + off) = acc[mt][nt] + xv;
        }
    }
}

extern "C" void kernel_launch(void* const* d_in, const int* in_sizes, int n_in,
                              void* d_out, int out_size, void* d_ws, size_t ws_size,
                              hipStream_t stream) {
    const float* x     = (const float*)d_in[0];
    const float* w_g   = (const float*)d_in[1];
    const float* b_g   = (const float*)d_in[2];
    const float* w_phi = (const float*)d_in[3];
    const float* b_phi = (const float*)d_in[4];
    float* out = (float*)d_out;

    char* ws = (char*)d_ws;
    _Float16* xT    = (_Float16*)(ws + OFF_XT);
    _Float16* Wc    = (_Float16*)(ws + OFF_WC);
    _Float16* theta = (_Float16*)(ws + OFF_THETA);
    _Float16* gT    = (_Float16*)(ws + OFF_GT);
    _Float16* phi   = (_Float16*)(ws + OFF_PHI);
    _Float16* attn  = (_Float16*)(ws + OFF_ATTN);

    k_prep_w<<<dim3(256), 256, 0, stream>>>(w_g, w_phi, Wc);
    k_prep_x<<<dim3(32, 16, 32), 256, 0, stream>>>(x, xT, theta);
    k_gemm1<<<dim3(32, 4, 32), 256, 0, stream>>>(Wc, xT, b_g, b_phi, gT, phi);
    k_gemm2<<<dim3(32, 32), 256, 0, stream>>>(theta, phi, attn);
    k_gemm3<<<dim3(32, 4, 32), 256, 0, stream>>>(attn, gT, x, out);
}

// Round 4
// 776.657 us; speedup vs baseline: 1.2112x; 1.2112x over previous
//
#include <hip/hip_runtime.h>

// SelfAttentionBlock channel-attention, MI355X fp16-MFMA pipeline.
// N=32, C=512, A=256, H=W=64 (P=4096 flat spatial, PP=1024 pooled).

typedef _Float16 half8 __attribute__((ext_vector_type(8)));
typedef _Float16 half4v __attribute__((ext_vector_type(4)));
typedef float f32x4 __attribute__((ext_vector_type(4)));

#define NB 32
#define CD 512
#define AD 256
#define PD 4096
#define PPD 1024

// ---------------- workspace layout (bytes) ----------------
#define OFF_XT    0UL
#define OFF_WC    134217728UL
#define OFF_THETA 134742016UL
#define OFF_GT    168296448UL
#define OFF_PHI   235405312UL
#define OFF_ATTN  252182528UL

// global->LDS direct (16B/lane). dest must be linear in lane (wave-uniform base + lane*16).
#define GLOAD16(gp, lp) \
    __builtin_amdgcn_global_load_lds((const __attribute__((address_space(1))) void*)(gp), \
                                     (__attribute__((address_space(3))) void*)(lp), 16, 0, 0)

// XOR-swizzled LDS tile [128 rows][32 halves], chunk = 16B (8 halves), 4 chunks/row.
// physical chunk chP at row holds logical chunk chP ^ ((row>>1)&3)  (involution).
__device__ __forceinline__ int swz_off(int row, int q) {
    return row * 32 + ((q ^ ((row >> 1) & 3)) * 8);
}

// Stage one 128x32 A-tile + 128x32 B-tile into LDS via global_load_lds,
// with source pre-swizzled so LDS dest stays linear. LD = row stride (halves).
// 4 global_load_lds per thread (vmcnt +=4).
template <int LD>
__device__ __forceinline__ void stage2(const _Float16* __restrict__ Ab,
                                       const _Float16* __restrict__ Bb,
                                       int k0, _Float16* bufA, _Float16* bufB, int t) {
#pragma unroll
    for (int j = 0; j < 4; ++j) {
        int idx = j * 256 + t;            // 0..1023 chunks (512 A + 512 B)
        int ci = idx & 511;
        int row = ci >> 2, chP = ci & 3;
        int chL = chP ^ ((row >> 1) & 3);
        const _Float16* src = ((idx < 512) ? Ab : Bb) + (size_t)row * LD + k0 + chL * 8;
        _Float16* dst = ((idx < 512) ? bufA : bufB) + ci * 8;
        GLOAD16(src, dst);
    }
}

__global__ __launch_bounds__(256) void k_prep_w(const float* __restrict__ w_g,
                                                const float* __restrict__ w_phi,
                                                _Float16* __restrict__ Wc) {
    int idx4 = blockIdx.x * 256 + threadIdx.x;
    int flat = idx4 * 4;
    const float* src = (flat < AD * CD) ? (w_g + flat) : (w_phi + (flat - AD * CD));
    float4 v = *(const float4*)src;
    half4v h;
    h[0] = (_Float16)v.x; h[1] = (_Float16)v.y; h[2] = (_Float16)v.z; h[3] = (_Float16)v.w;
    *(half4v*)(Wc + flat) = h;
}

// Read x fp32 tile (32 c x 128 p), produce xT fp16 (transposed) + theta (pooled).
__global__ __launch_bounds__(256) void k_prep_x(const float* __restrict__ x,
                                                _Float16* __restrict__ xT,
                                                _Float16* __restrict__ theta) {
    __shared__ _Float16 tile[32 * 136];
    int pb = blockIdx.x;
    int cb = blockIdx.y;
    int n  = blockIdx.z;
    int t  = threadIdx.x;
    int p0 = pb * 128, c0 = cb * 32;

    const float* xbase = x + ((size_t)n * CD + c0) * PD + p0;
#pragma unroll
    for (int i = 0; i < 4; ++i) {
        int idx = i * 256 + t;
        int cl = idx >> 5;
        int ch = idx & 31;
        float4 v = *(const float4*)(xbase + (size_t)cl * PD + ch * 4);
        half4v h;
        h[0] = (_Float16)v.x; h[1] = (_Float16)v.y; h[2] = (_Float16)v.z; h[3] = (_Float16)v.w;
        *(half4v*)&tile[cl * 136 + ch * 4] = h;
    }
    __syncthreads();

    {
        int pl = t >> 1, ch = t & 1;
        _Float16 vals[16] __attribute__((aligned(16)));
#pragma unroll
        for (int j = 0; j < 16; ++j) vals[j] = tile[(ch * 16 + j) * 136 + pl];
        _Float16* dst = xT + ((size_t)n * PD + p0 + pl) * CD + c0 + ch * 16;
        *(uint4*)dst       = *(uint4*)&vals[0];
        *(uint4*)(dst + 8) = *(uint4*)&vals[8];
    }
    {
        int cl = t >> 3, u0 = (t & 7) * 4;
        _Float16 o[4] __attribute__((aligned(8)));
#pragma unroll
        for (int j = 0; j < 4; ++j) {
            int w2 = (u0 + j) * 2;
            float a0 = (float)tile[cl * 136 + w2];
            float a1 = (float)tile[cl * 136 + w2 + 1];
            float a2 = (float)tile[cl * 136 + 64 + w2];
            float a3 = (float)tile[cl * 136 + 64 + w2 + 1];
            o[j] = (_Float16)fmaxf(fmaxf(a0, a1), fmaxf(a2, a3));
        }
        _Float16* dst = theta + ((size_t)n * CD + c0 + cl) * PPD + pb * 32 + u0;
        *(uint2*)dst = *(uint2*)&o[0];
    }
}

// GEMM1: D[a][p] = sum_c Wc[a][c] * x[c][p], 128x128 tile, K=512.
// 3-buffer counted-vmcnt global_load_lds pipeline (T4): per step wait vmcnt(4)
// so next tile's loads stay in flight across the barrier; stage k+2 after barrier.
__global__ __launch_bounds__(256) void k_gemm1(const _Float16* __restrict__ Wc,
                                               const _Float16* __restrict__ xT,
                                               const float* __restrict__ b_g,
                                               const float* __restrict__ b_phi,
                                               _Float16* __restrict__ gT,
                                               _Float16* __restrict__ phi) {
    // 3 bufs x (A 4096 + B 4096) halves = 24576 halves = 49152 B.
    // Epilogue reuses smem[0..17407] as [128][136].
    __shared__ _Float16 smem[24576];

    int pb = blockIdx.x, ab = blockIdx.y, n = blockIdx.z;
    int a0 = ab * 128, p0 = pb * 128;
    int t = threadIdx.x;
    int w = t >> 6, l = t & 63;
    int ln = l & 15, q = l >> 4;
    int mw = (w >> 1) * 64, nw = (w & 1) * 64;

    const f32x4 vzero = {0.f, 0.f, 0.f, 0.f};
    f32x4 acc[4][4];
#pragma unroll
    for (int i = 0; i < 4; ++i)
#pragma unroll
        for (int j = 0; j < 4; ++j) acc[i][j] = vzero;

    const _Float16* Abase = Wc + (size_t)a0 * CD;
    const _Float16* Bbase = xT + ((size_t)n * PD + p0) * CD;

    stage2<CD>(Abase, Bbase, 0, smem, smem + 4096, t);
    stage2<CD>(Abase, Bbase, 32, smem + 8192, smem + 8192 + 4096, t);

#pragma unroll
    for (int ks = 0; ks < 15; ++ks) {
        asm volatile("s_waitcnt vmcnt(4)" ::: "memory");   // stage(ks) done, stage(ks+1) in flight
        __builtin_amdgcn_s_barrier();
        __builtin_amdgcn_sched_barrier(0);
        if (ks + 2 < 16) {
            int ob = ((ks + 2) % 3) * 8192;
            stage2<CD>(Abase, Bbase, (ks + 2) * 32, smem + ob, smem + ob + 4096, t);
        }
        int oc = (ks % 3) * 8192;
        _Float16* As = smem + oc;
        _Float16* Bs = smem + oc + 4096;
        half8 af[4], bf[4];
#pragma unroll
        for (int mt = 0; mt < 4; ++mt) af[mt] = *(const half8*)&As[swz_off(mw + mt * 16 + ln, q)];
#pragma unroll
        for (int nt = 0; nt < 4; ++nt) bf[nt] = *(const half8*)&Bs[swz_off(nw + nt * 16 + ln, q)];
#pragma unroll
        for (int mt = 0; mt < 4; ++mt)
#pragma unroll
            for (int nt = 0; nt < 4; ++nt)
                acc[mt][nt] = __builtin_amdgcn_mfma_f32_16x16x32_f16(af[mt], bf[nt], acc[mt][nt], 0, 0, 0);
    }
    // peeled last step: only stage(15) outstanding -> full drain
    asm volatile("s_waitcnt vmcnt(0)" ::: "memory");
    __builtin_amdgcn_s_barrier();
    __builtin_amdgcn_sched_barrier(0);
    {
        int oc = (15 % 3) * 8192;
        _Float16* As = smem + oc;
        _Float16* Bs = smem + oc + 4096;
        half8 af[4], bf[4];
#pragma unroll
        for (int mt = 0; mt < 4; ++mt) af[mt] = *(const half8*)&As[swz_off(mw + mt * 16 + ln, q)];
#pragma unroll
        for (int nt = 0; nt < 4; ++nt) bf[nt] = *(const half8*)&Bs[swz_off(nw + nt * 16 + ln, q)];
#pragma unroll
        for (int mt = 0; mt < 4; ++mt)
#pragma unroll
            for (int nt = 0; nt < 4; ++nt)
                acc[mt][nt] = __builtin_amdgcn_mfma_f32_16x16x32_f16(af[mt], bf[nt], acc[mt][nt], 0, 0, 0);
    }
    __syncthreads();   // all waves done with staging buffers before LDS reuse

    bool is_g = (a0 < 256);
    const float* bias = is_g ? b_g : b_phi;
    int abase = a0 - (is_g ? 0 : 256);
    float bv[4][4];
#pragma unroll
    for (int mt = 0; mt < 4; ++mt)
#pragma unroll
        for (int r = 0; r < 4; ++r) bv[mt][r] = bias[abase + mw + mt * 16 + q * 4 + r];

    _Float16* T = smem;   // [row][136]
    if (is_g) {
#pragma unroll
        for (int mt = 0; mt < 4; ++mt)
#pragma unroll
            for (int nt = 0; nt < 4; ++nt)
#pragma unroll
                for (int r = 0; r < 4; ++r) {
                    int al = mw + mt * 16 + q * 4 + r;
                    int pl = nw + nt * 16 + ln;
                    T[pl * 136 + al] = (_Float16)(acc[mt][nt][r] + bv[mt][r]);
                }
        __syncthreads();
#pragma unroll
        for (int i = 0; i < 8; ++i) {
            int idx = i * 256 + t;
            int pl = idx >> 4, ch = idx & 15;
            uint4 v = *(uint4*)&T[pl * 136 + ch * 8];
            *(uint4*)(gT + ((size_t)n * PD + p0 + pl) * AD + a0 + ch * 8) = v;
        }
    } else {
#pragma unroll
        for (int mt = 0; mt < 4; ++mt)
#pragma unroll
            for (int nt = 0; nt < 4; ++nt)
#pragma unroll
                for (int r = 0; r < 4; ++r) {
                    int al = mw + mt * 16 + q * 4 + r;
                    int pl = nw + nt * 16 + ln;
                    T[al * 136 + pl] = (_Float16)(acc[mt][nt][r] + bv[mt][r]);
                }
        __syncthreads();
        int al = t >> 1, hf = t & 1;
        _Float16 o[16] __attribute__((aligned(16)));
#pragma unroll
        for (int j = 0; j < 16; ++j) {
            int u = hf * 16 + j;
            float v0 = (float)T[al * 136 + 2 * u];
            float v1 = (float)T[al * 136 + 2 * u + 1];
            float v2 = (float)T[al * 136 + 64 + 2 * u];
            float v3 = (float)T[al * 136 + 64 + 2 * u + 1];
            o[j] = (_Float16)fmaxf(fmaxf(v0, v1), fmaxf(v2, v3));
        }
        _Float16* dst = phi + ((size_t)n * AD + (a0 - 256) + al) * PPD + pb * 32 + hf * 16;
        *(uint4*)dst       = *(uint4*)&o[0];
        *(uint4*)(dst + 8) = *(uint4*)&o[8];
    }
}

// GEMM2 + softmax, K-split across waves for occupancy.
__global__ __launch_bounds__(256) void k_gemm2(const _Float16* __restrict__ theta,
                                               const _Float16* __restrict__ phi,
                                               _Float16* __restrict__ attn) {
    __shared__ float red[3 * 64 * 65];
    int cb = blockIdx.x;   // 0..31
    int n  = blockIdx.y;
    int t = threadIdx.x, w = t >> 6, l = t & 63;
    int ln = l & 15, q = l >> 4;
    int c0 = cb * 16;

    const _Float16* Ab = theta + ((size_t)n * CD + c0 + ln) * PPD + w * 256;
    const _Float16* Bb = phi + ((size_t)n * AD + ln) * PPD + w * 256;

    const f32x4 vzero = {0.f, 0.f, 0.f, 0.f};
    f32x4 acc[16];
#pragma unroll
    for (int i = 0; i < 16; ++i) acc[i] = vzero;

    for (int k0 = 0; k0 < 256; k0 += 32) {
        half8 af = *(const half8*)(Ab + k0 + q * 8);
#pragma unroll
        for (int nt = 0; nt < 16; ++nt) {
            half8 bf = *(const half8*)(Bb + (size_t)nt * 16 * PPD + k0 + q * 8);
            acc[nt] = __builtin_amdgcn_mfma_f32_16x16x32_f16(af, bf, acc[nt], 0, 0, 0);
        }
    }

    if (w > 0) {
        float* dst = red + (w - 1) * 64 * 65 + l * 65;
#pragma unroll
        for (int nt = 0; nt < 16; ++nt)
#pragma unroll
            for (int r = 0; r < 4; ++r) dst[nt * 4 + r] = acc[nt][r];
    }
    __syncthreads();
    if (w == 0) {
#pragma unroll
        for (int j = 0; j < 3; ++j) {
            const float* src = red + j * 64 * 65 + l * 65;
#pragma unroll
            for (int nt = 0; nt < 16; ++nt)
#pragma unroll
                for (int r = 0; r < 4; ++r) acc[nt][r] += src[nt * 4 + r];
        }
#pragma unroll
        for (int r = 0; r < 4; ++r) {
            float m = -1e30f;
#pragma unroll
            for (int nt = 0; nt < 16; ++nt) m = fmaxf(m, acc[nt][r]);
#pragma unroll
            for (int s = 1; s < 16; s <<= 1) m = fmaxf(m, __shfl_xor(m, s, 64));
            float sum = 0.f;
#pragma unroll
            for (int nt = 0; nt < 16; ++nt) {
                float e = __expf(acc[nt][r] - m);
                acc[nt][r] = e;
                sum += e;
            }
#pragma unroll
            for (int s = 1; s < 16; s <<= 1) sum += __shfl_xor(sum, s, 64);
            float inv = 1.0f / sum;
            int c = c0 + q * 4 + r;
            _Float16* dst = attn + ((size_t)n * CD + c) * AD + ln;
#pragma unroll
            for (int nt = 0; nt < 16; ++nt) dst[nt * 16] = (_Float16)(acc[nt][r] * inv);
        }
    }
}

// GEMM3: out[c][p] = sum_a attn[c][a] * gT[p][a] + x[c][p].  128x128 tile, K=256.
// Operand-swapped (D[p][c] -> float4 epilogue); 3-buffer counted-vmcnt pipeline;
// nontemporal x/out streaming (keeps gT/attn resident in L2).
__global__ __launch_bounds__(256) void k_gemm3(const _Float16* __restrict__ attn,
                                               const _Float16* __restrict__ gT,
                                               const float* __restrict__ x,
                                               float* __restrict__ out) {
    __shared__ _Float16 smem[24576];   // 3 bufs x (As 4096 + Bs 4096)

    int pb = blockIdx.x, cb = blockIdx.y, n = blockIdx.z;
    int c0 = cb * 128, p0 = pb * 128;
    int t = threadIdx.x;
    int w = t >> 6, l = t & 63;
    int ln = l & 15, q = l >> 4;
    int mw = (w >> 1) * 64, nw = (w & 1) * 64;   // mw: p-tile, nw: c-tile

    const f32x4 vzero = {0.f, 0.f, 0.f, 0.f};
    f32x4 acc[4][4];
#pragma unroll
    for (int i = 0; i < 4; ++i)
#pragma unroll
        for (int j = 0; j < 4; ++j) acc[i][j] = vzero;

    const _Float16* Abase = attn + ((size_t)n * CD + c0) * AD;   // 128 c rows
    const _Float16* Bbase = gT + ((size_t)n * PD + p0) * AD;     // 128 p rows

    stage2<AD>(Abase, Bbase, 0, smem, smem + 4096, t);
    stage2<AD>(Abase, Bbase, 32, smem + 8192, smem + 8192 + 4096, t);

#pragma unroll
    for (int ks = 0; ks < 7; ++ks) {
        asm volatile("s_waitcnt vmcnt(4)" ::: "memory");
        __builtin_amdgcn_s_barrier();
        __builtin_amdgcn_sched_barrier(0);
        if (ks + 2 < 8) {
            int ob = ((ks + 2) % 3) * 8192;
            stage2<AD>(Abase, Bbase, (ks + 2) * 32, smem + ob, smem + ob + 4096, t);
        }
        int oc = (ks % 3) * 8192;
        _Float16* As = smem + oc;          // attn tile (c rows)
        _Float16* Bs = smem + oc + 4096;   // gT tile (p rows)
        half8 af[4], bf[4];
        // A-operand = gT rows (p) -> D rows = p; B-operand = attn rows (c) -> D cols = c
#pragma unroll
        for (int mt = 0; mt < 4; ++mt) af[mt] = *(const half8*)&Bs[swz_off(mw + mt * 16 + ln, q)];
#pragma unroll
        for (int nt = 0; nt < 4; ++nt) bf[nt] = *(const half8*)&As[swz_off(nw + nt * 16 + ln, q)];
#pragma unroll
        for (int mt = 0; mt < 4; ++mt)
#pragma unroll
            for (int nt = 0; nt < 4; ++nt)
                acc[mt][nt] = __builtin_amdgcn_mfma_f32_16x16x32_f16(af[mt], bf[nt], acc[mt][nt], 0, 0, 0);
    }
    asm volatile("s_waitcnt vmcnt(0)" ::: "memory");
    __builtin_amdgcn_s_barrier();
    __builtin_amdgcn_sched_barrier(0);
    {
        int oc = (7 % 3) * 8192;
        _Float16* As = smem + oc;
        _Float16* Bs = smem + oc + 4096;
        half8 af[4], bf[4];
#pragma unroll
        for (int mt = 0; mt < 4; ++mt) af[mt] = *(const half8*)&Bs[swz_off(mw + mt * 16 + ln, q)];
#pragma unroll
        for (int nt = 0; nt < 4; ++nt) bf[nt] = *(const half8*)&As[swz_off(nw + nt * 16 + ln, q)];
#pragma unroll
        for (int mt = 0; mt < 4; ++mt)
#pragma unroll
            for (int nt = 0; nt < 4; ++nt)
                acc[mt][nt] = __builtin_amdgcn_mfma_f32_16x16x32_f16(af[mt], bf[nt], acc[mt][nt], 0, 0, 0);
    }

    // epilogue: lane (q,ln) of tile (mt,nt) holds p = p0+mw+mt*16+q*4..+3, c = c0+nw+nt*16+ln.
    // Per-mt batch: 4 nontemporal f32x4 x-loads, add, 4 nontemporal stores.
#pragma unroll
    for (int mt = 0; mt < 4; ++mt) {
        int p = p0 + mw + mt * 16 + q * 4;
        size_t offs[4];
        f32x4 xv[4];
#pragma unroll
        for (int nt = 0; nt < 4; ++nt) {
            int c = c0 + nw + nt * 16 + ln;
            offs[nt] = ((size_t)n * CD + c) * PD + p;
            xv[nt] = __builtin_nontemporal_load((const f32x4*)(x + offs[nt]));
        }
#pragma unroll
        for (int nt = 0; nt < 4; ++nt) {
            f32x4 r = acc[mt][nt] + xv[nt];
            __builtin_nontemporal_store(r, (f32x4*)(out + offs[nt]));
        }
    }
}

extern "C" void kernel_launch(void* const* d_in, const int* in_sizes, int n_in,
                              void* d_out, int out_size, void* d_ws, size_t ws_size,
                              hipStream_t stream) {
    const float* x     = (const float*)d_in[0];
    const float* w_g   = (const float*)d_in[1];
    const float* b_g   = (const float*)d_in[2];
    const float* w_phi = (const float*)d_in[3];
    const float* b_phi = (const float*)d_in[4];
    float* out = (float*)d_out;

    char* ws = (char*)d_ws;
    _Float16* xT    = (_Float16*)(ws + OFF_XT);
    _Float16* Wc    = (_Float16*)(ws + OFF_WC);
    _Float16* theta = (_Float16*)(ws + OFF_THETA);
    _Float16* gT    = (_Float16*)(ws + OFF_GT);
    _Float16* phi   = (_Float16*)(ws + OFF_PHI);
    _Float16* attn  = (_Float16*)(ws + OFF_ATTN);

    k_prep_w<<<dim3(256), 256, 0, stream>>>(w_g, w_phi, Wc);
    k_prep_x<<<dim3(32, 16, 32), 256, 0, stream>>>(x, xT, theta);
    k_gemm1<<<dim3(32, 4, 32), 256, 0, stream>>>(Wc, xT, b_g, b_phi, gT, phi);
    k_gemm2<<<dim3(32, 32), 256, 0, stream>>>(theta, phi, attn);
    k_gemm3<<<dim3(32, 4, 32), 256, 0, stream>>>(attn, gT, x, out);
}

// Round 5
// 762.500 us; speedup vs baseline: 1.2336x; 1.0186x over previous
//
#include <hip/hip_runtime.h>

// SelfAttentionBlock channel-attention, MI355X fp16-MFMA pipeline.
// N=32, C=512, A=256, H=W=64 (P=4096 flat spatial, PP=1024 pooled).

typedef _Float16 half8 __attribute__((ext_vector_type(8)));
typedef _Float16 half4v __attribute__((ext_vector_type(4)));
typedef float f32x4 __attribute__((ext_vector_type(4)));

#define NB 32
#define CD 512
#define AD 256
#define PD 4096
#define PPD 1024

// ---------------- workspace layout (bytes) ----------------
#define OFF_XT    0UL
#define OFF_WC    134217728UL
#define OFF_THETA 134742016UL
#define OFF_GT    168296448UL
#define OFF_PHI   235405312UL
#define OFF_ATTN  252182528UL

// global->LDS direct (16B/lane). dest must be linear in lane (wave-uniform base + lane*16).
#define GLOAD16(gp, lp) \
    __builtin_amdgcn_global_load_lds((const __attribute__((address_space(1))) void*)(gp), \
                                     (__attribute__((address_space(3))) void*)(lp), 16, 0, 0)

// XOR-swizzled LDS tile [128 rows][32 halves], chunk = 16B (8 halves), 4 chunks/row.
// physical chunk chP at row holds logical chunk chP ^ ((row>>1)&3)  (involution).
__device__ __forceinline__ int swz_off(int row, int q) {
    return row * 32 + ((q ^ ((row >> 1) & 3)) * 8);
}

// Stage one 128x32 A-tile + 128x32 B-tile into LDS via global_load_lds,
// with source pre-swizzled so LDS dest stays linear. LD = row stride (halves).
// 4 global_load_lds per thread (vmcnt +=4).
template <int LD>
__device__ __forceinline__ void stage2(const _Float16* __restrict__ Ab,
                                       const _Float16* __restrict__ Bb,
                                       int k0, _Float16* bufA, _Float16* bufB, int t) {
#pragma unroll
    for (int j = 0; j < 4; ++j) {
        int idx = j * 256 + t;            // 0..1023 chunks (512 A + 512 B)
        int ci = idx & 511;
        int row = ci >> 2, chP = ci & 3;
        int chL = chP ^ ((row >> 1) & 3);
        const _Float16* src = ((idx < 512) ? Ab : Bb) + (size_t)row * LD + k0 + chL * 8;
        _Float16* dst = ((idx < 512) ? bufA : bufB) + ci * 8;
        GLOAD16(src, dst);
    }
}

__global__ __launch_bounds__(256) void k_prep_w(const float* __restrict__ w_g,
                                                const float* __restrict__ w_phi,
                                                _Float16* __restrict__ Wc) {
    int idx4 = blockIdx.x * 256 + threadIdx.x;
    int flat = idx4 * 4;
    const float* src = (flat < AD * CD) ? (w_g + flat) : (w_phi + (flat - AD * CD));
    float4 v = *(const float4*)src;
    half4v h;
    h[0] = (_Float16)v.x; h[1] = (_Float16)v.y; h[2] = (_Float16)v.z; h[3] = (_Float16)v.w;
    *(half4v*)(Wc + flat) = h;
}

// Read x fp32 tile (32 c x 128 p), produce xT fp16 (transposed) + theta (pooled).
__global__ __launch_bounds__(256) void k_prep_x(const float* __restrict__ x,
                                                _Float16* __restrict__ xT,
                                                _Float16* __restrict__ theta) {
    __shared__ _Float16 tile[32 * 136];
    int pb = blockIdx.x;
    int cb = blockIdx.y;
    int n  = blockIdx.z;
    int t  = threadIdx.x;
    int p0 = pb * 128, c0 = cb * 32;

    const float* xbase = x + ((size_t)n * CD + c0) * PD + p0;
#pragma unroll
    for (int i = 0; i < 4; ++i) {
        int idx = i * 256 + t;
        int cl = idx >> 5;
        int ch = idx & 31;
        float4 v = *(const float4*)(xbase + (size_t)cl * PD + ch * 4);
        half4v h;
        h[0] = (_Float16)v.x; h[1] = (_Float16)v.y; h[2] = (_Float16)v.z; h[3] = (_Float16)v.w;
        *(half4v*)&tile[cl * 136 + ch * 4] = h;
    }
    __syncthreads();

    {
        int pl = t >> 1, ch = t & 1;
        _Float16 vals[16] __attribute__((aligned(16)));
#pragma unroll
        for (int j = 0; j < 16; ++j) vals[j] = tile[(ch * 16 + j) * 136 + pl];
        _Float16* dst = xT + ((size_t)n * PD + p0 + pl) * CD + c0 + ch * 16;
        *(uint4*)dst       = *(uint4*)&vals[0];
        *(uint4*)(dst + 8) = *(uint4*)&vals[8];
    }
    {
        int cl = t >> 3, u0 = (t & 7) * 4;
        _Float16 o[4] __attribute__((aligned(8)));
#pragma unroll
        for (int j = 0; j < 4; ++j) {
            int w2 = (u0 + j) * 2;
            float a0 = (float)tile[cl * 136 + w2];
            float a1 = (float)tile[cl * 136 + w2 + 1];
            float a2 = (float)tile[cl * 136 + 64 + w2];
            float a3 = (float)tile[cl * 136 + 64 + w2 + 1];
            o[j] = (_Float16)fmaxf(fmaxf(a0, a1), fmaxf(a2, a3));
        }
        _Float16* dst = theta + ((size_t)n * CD + c0 + cl) * PPD + pb * 32 + u0;
        *(uint2*)dst = *(uint2*)&o[0];
    }
}

// GEMM1: D[a][p] = sum_c Wc[a][c] * x[c][p], 128x128 tile, K=512.
// 3-buffer counted-vmcnt global_load_lds pipeline (round-4 config, best so far).
__global__ __launch_bounds__(256) void k_gemm1(const _Float16* __restrict__ Wc,
                                               const _Float16* __restrict__ xT,
                                               const float* __restrict__ b_g,
                                               const float* __restrict__ b_phi,
                                               _Float16* __restrict__ gT,
                                               _Float16* __restrict__ phi) {
    // 3 bufs x (A 4096 + B 4096) halves = 24576 halves = 49152 B.
    // Epilogue reuses smem[0..17407] as [128][136].
    __shared__ _Float16 smem[24576];

    int pb = blockIdx.x, ab = blockIdx.y, n = blockIdx.z;
    int a0 = ab * 128, p0 = pb * 128;
    int t = threadIdx.x;
    int w = t >> 6, l = t & 63;
    int ln = l & 15, q = l >> 4;
    int mw = (w >> 1) * 64, nw = (w & 1) * 64;

    const f32x4 vzero = {0.f, 0.f, 0.f, 0.f};
    f32x4 acc[4][4];
#pragma unroll
    for (int i = 0; i < 4; ++i)
#pragma unroll
        for (int j = 0; j < 4; ++j) acc[i][j] = vzero;

    const _Float16* Abase = Wc + (size_t)a0 * CD;
    const _Float16* Bbase = xT + ((size_t)n * PD + p0) * CD;

    stage2<CD>(Abase, Bbase, 0, smem, smem + 4096, t);
    stage2<CD>(Abase, Bbase, 32, smem + 8192, smem + 8192 + 4096, t);

#pragma unroll
    for (int ks = 0; ks < 15; ++ks) {
        asm volatile("s_waitcnt vmcnt(4)" ::: "memory");   // stage(ks) done, stage(ks+1) in flight
        __builtin_amdgcn_s_barrier();
        __builtin_amdgcn_sched_barrier(0);
        if (ks + 2 < 16) {
            int ob = ((ks + 2) % 3) * 8192;
            stage2<CD>(Abase, Bbase, (ks + 2) * 32, smem + ob, smem + ob + 4096, t);
        }
        int oc = (ks % 3) * 8192;
        _Float16* As = smem + oc;
        _Float16* Bs = smem + oc + 4096;
        half8 af[4], bf[4];
#pragma unroll
        for (int mt = 0; mt < 4; ++mt) af[mt] = *(const half8*)&As[swz_off(mw + mt * 16 + ln, q)];
#pragma unroll
        for (int nt = 0; nt < 4; ++nt) bf[nt] = *(const half8*)&Bs[swz_off(nw + nt * 16 + ln, q)];
#pragma unroll
        for (int mt = 0; mt < 4; ++mt)
#pragma unroll
            for (int nt = 0; nt < 4; ++nt)
                acc[mt][nt] = __builtin_amdgcn_mfma_f32_16x16x32_f16(af[mt], bf[nt], acc[mt][nt], 0, 0, 0);
    }
    // peeled last step: only stage(15) outstanding -> full drain
    asm volatile("s_waitcnt vmcnt(0)" ::: "memory");
    __builtin_amdgcn_s_barrier();
    __builtin_amdgcn_sched_barrier(0);
    {
        int oc = (15 % 3) * 8192;
        _Float16* As = smem + oc;
        _Float16* Bs = smem + oc + 4096;
        half8 af[4], bf[4];
#pragma unroll
        for (int mt = 0; mt < 4; ++mt) af[mt] = *(const half8*)&As[swz_off(mw + mt * 16 + ln, q)];
#pragma unroll
        for (int nt = 0; nt < 4; ++nt) bf[nt] = *(const half8*)&Bs[swz_off(nw + nt * 16 + ln, q)];
#pragma unroll
        for (int mt = 0; mt < 4; ++mt)
#pragma unroll
            for (int nt = 0; nt < 4; ++nt)
                acc[mt][nt] = __builtin_amdgcn_mfma_f32_16x16x32_f16(af[mt], bf[nt], acc[mt][nt], 0, 0, 0);
    }
    __syncthreads();   // all waves done with staging buffers before LDS reuse

    bool is_g = (a0 < 256);
    const float* bias = is_g ? b_g : b_phi;
    int abase = a0 - (is_g ? 0 : 256);
    float bv[4][4];
#pragma unroll
    for (int mt = 0; mt < 4; ++mt)
#pragma unroll
        for (int r = 0; r < 4; ++r) bv[mt][r] = bias[abase + mw + mt * 16 + q * 4 + r];

    _Float16* T = smem;   // [row][136]
    if (is_g) {
#pragma unroll
        for (int mt = 0; mt < 4; ++mt)
#pragma unroll
            for (int nt = 0; nt < 4; ++nt)
#pragma unroll
                for (int r = 0; r < 4; ++r) {
                    int al = mw + mt * 16 + q * 4 + r;
                    int pl = nw + nt * 16 + ln;
                    T[pl * 136 + al] = (_Float16)(acc[mt][nt][r] + bv[mt][r]);
                }
        __syncthreads();
#pragma unroll
        for (int i = 0; i < 8; ++i) {
            int idx = i * 256 + t;
            int pl = idx >> 4, ch = idx & 15;
            uint4 v = *(uint4*)&T[pl * 136 + ch * 8];
            *(uint4*)(gT + ((size_t)n * PD + p0 + pl) * AD + a0 + ch * 8) = v;
        }
    } else {
#pragma unroll
        for (int mt = 0; mt < 4; ++mt)
#pragma unroll
            for (int nt = 0; nt < 4; ++nt)
#pragma unroll
                for (int r = 0; r < 4; ++r) {
                    int al = mw + mt * 16 + q * 4 + r;
                    int pl = nw + nt * 16 + ln;
                    T[al * 136 + pl] = (_Float16)(acc[mt][nt][r] + bv[mt][r]);
                }
        __syncthreads();
        int al = t >> 1, hf = t & 1;
        _Float16 o[16] __attribute__((aligned(16)));
#pragma unroll
        for (int j = 0; j < 16; ++j) {
            int u = hf * 16 + j;
            float v0 = (float)T[al * 136 + 2 * u];
            float v1 = (float)T[al * 136 + 2 * u + 1];
            float v2 = (float)T[al * 136 + 64 + 2 * u];
            float v3 = (float)T[al * 136 + 64 + 2 * u + 1];
            o[j] = (_Float16)fmaxf(fmaxf(v0, v1), fmaxf(v2, v3));
        }
        _Float16* dst = phi + ((size_t)n * AD + (a0 - 256) + al) * PPD + pb * 32 + hf * 16;
        *(uint4*)dst       = *(uint4*)&o[0];
        *(uint4*)(dst + 8) = *(uint4*)&o[8];
    }
}

// GEMM2 + softmax, K-split across waves for occupancy.
__global__ __launch_bounds__(256) void k_gemm2(const _Float16* __restrict__ theta,
                                               const _Float16* __restrict__ phi,
                                               _Float16* __restrict__ attn) {
    __shared__ float red[3 * 64 * 65];
    int cb = blockIdx.x;   // 0..31
    int n  = blockIdx.y;
    int t = threadIdx.x, w = t >> 6, l = t & 63;
    int ln = l & 15, q = l >> 4;
    int c0 = cb * 16;

    const _Float16* Ab = theta + ((size_t)n * CD + c0 + ln) * PPD + w * 256;
    const _Float16* Bb = phi + ((size_t)n * AD + ln) * PPD + w * 256;

    const f32x4 vzero = {0.f, 0.f, 0.f, 0.f};
    f32x4 acc[16];
#pragma unroll
    for (int i = 0; i < 16; ++i) acc[i] = vzero;

    for (int k0 = 0; k0 < 256; k0 += 32) {
        half8 af = *(const half8*)(Ab + k0 + q * 8);
#pragma unroll
        for (int nt = 0; nt < 16; ++nt) {
            half8 bf = *(const half8*)(Bb + (size_t)nt * 16 * PPD + k0 + q * 8);
            acc[nt] = __builtin_amdgcn_mfma_f32_16x16x32_f16(af, bf, acc[nt], 0, 0, 0);
        }
    }

    if (w > 0) {
        float* dst = red + (w - 1) * 64 * 65 + l * 65;
#pragma unroll
        for (int nt = 0; nt < 16; ++nt)
#pragma unroll
            for (int r = 0; r < 4; ++r) dst[nt * 4 + r] = acc[nt][r];
    }
    __syncthreads();
    if (w == 0) {
#pragma unroll
        for (int j = 0; j < 3; ++j) {
            const float* src = red + j * 64 * 65 + l * 65;
#pragma unroll
            for (int nt = 0; nt < 16; ++nt)
#pragma unroll
                for (int r = 0; r < 4; ++r) acc[nt][r] += src[nt * 4 + r];
        }
#pragma unroll
        for (int r = 0; r < 4; ++r) {
            float m = -1e30f;
#pragma unroll
            for (int nt = 0; nt < 16; ++nt) m = fmaxf(m, acc[nt][r]);
#pragma unroll
            for (int s = 1; s < 16; s <<= 1) m = fmaxf(m, __shfl_xor(m, s, 64));
            float sum = 0.f;
#pragma unroll
            for (int nt = 0; nt < 16; ++nt) {
                float e = __expf(acc[nt][r] - m);
                acc[nt][r] = e;
                sum += e;
            }
#pragma unroll
            for (int s = 1; s < 16; s <<= 1) sum += __shfl_xor(sum, s, 64);
            float inv = 1.0f / sum;
            int c = c0 + q * 4 + r;
            _Float16* dst = attn + ((size_t)n * CD + c) * AD + ln;
#pragma unroll
            for (int nt = 0; nt < 16; ++nt) dst[nt * 16] = (_Float16)(acc[nt][r] * inv);
        }
    }
}

// GEMM3: out[c][p] = sum_a attn[c][a] * gT[p][a] + x[c][p].  128x128 tile, K=256.
// Operand-swapped (D[p][c] -> float4 epilogue). Hybrid operand feed:
//   gT (A-op)  : LDS-staged, 2 bufs x [128][32] swizzled = 16 KB, 2 gload_lds/thread/step.
//   attn (B-op): direct global->reg, software-pipelined one k-step ahead (L2-resident,
//                reused by 32 pb-blocks). No vmcnt(0) drain of bf loads at barriers.
// Entry protocol/step: vmcnt(4) [drains 2 stage loads, leaves 4 bf loads] -> raw barrier.
// Epilogue: 16-deep batched x loads (MLP) + nontemporal stores.
__global__ __launch_bounds__(256) void k_gemm3(const _Float16* __restrict__ attn,
                                               const _Float16* __restrict__ gT,
                                               const float* __restrict__ x,
                                               float* __restrict__ out) {
    __shared__ _Float16 smem[8192];   // 2 bufs x [128 p-rows][32 k] gT

    int pb = blockIdx.x, cb = blockIdx.y, n = blockIdx.z;
    int c0 = cb * 128, p0 = pb * 128;
    int t = threadIdx.x;
    int w = t >> 6, l = t & 63;
    int ln = l & 15, q = l >> 4;
    int mw = (w >> 1) * 64, nw = (w & 1) * 64;   // mw: p-tile, nw: c-tile

    const f32x4 vzero = {0.f, 0.f, 0.f, 0.f};
    f32x4 acc[4][4];
#pragma unroll
    for (int i = 0; i < 4; ++i)
#pragma unroll
        for (int j = 0; j < 4; ++j) acc[i][j] = vzero;

    const _Float16* Bbase = gT + ((size_t)n * PD + p0) * AD;     // 128 p rows (staged)
    const _Float16* brow[4];                                      // attn rows (direct)
#pragma unroll
    for (int nt = 0; nt < 4; ++nt)
        brow[nt] = attn + ((size_t)n * CD + c0 + nw + nt * 16 + ln) * AD + q * 8;

    // stage gT k-tile (128 rows x 32 halves = 512 chunks, 2 per thread)
    auto stageB = [&](int k0, _Float16* buf) {
#pragma unroll
        for (int j = 0; j < 2; ++j) {
            int idx = j * 256 + t;
            int row = idx >> 2, chP = idx & 3;
            int chL = chP ^ ((row >> 1) & 3);
            GLOAD16(Bbase + (size_t)row * AD + k0 + chL * 8, buf + idx * 8);
        }
    };

    half8 bfA[4], bfB[4];

    // prologue: stage(0) + bf(0); order pinned so vmcnt accounting holds
    stageB(0, smem);
    __builtin_amdgcn_sched_barrier(0);
#pragma unroll
    for (int nt = 0; nt < 4; ++nt) bfA[nt] = *(const half8*)(brow[nt]);

    // one K-step: entry wait+barrier, issue stage(ks+1)+bf(ks+1), compute(ks)
    auto step = [&](int ks, _Float16* Bs_cur, _Float16* Bs_nxt,
                    half8 (&bfc)[4], half8 (&bfn)[4], bool issue) {
        asm volatile("s_waitcnt vmcnt(4)" ::: "memory");   // stage(ks) landed; bf(ks) may fly
        __builtin_amdgcn_s_barrier();
        __builtin_amdgcn_sched_barrier(0);
        if (issue) {
            stageB((ks + 1) * 32, Bs_nxt);                 // 2 loads (oldest of this iter)
            __builtin_amdgcn_sched_barrier(0);             // pin: stage before bf
#pragma unroll
            for (int nt = 0; nt < 4; ++nt) bfn[nt] = *(const half8*)(brow[nt] + (ks + 1) * 32);
        }
        half8 af[4];
#pragma unroll
        for (int mt = 0; mt < 4; ++mt) af[mt] = *(const half8*)&Bs_cur[swz_off(mw + mt * 16 + ln, q)];
#pragma unroll
        for (int mt = 0; mt < 4; ++mt)
#pragma unroll
            for (int nt = 0; nt < 4; ++nt)
                acc[mt][nt] = __builtin_amdgcn_mfma_f32_16x16x32_f16(af[mt], bfc[nt], acc[mt][nt], 0, 0, 0);
    };

    _Float16* b0 = smem;
    _Float16* b1 = smem + 4096;
    for (int ks2 = 0; ks2 < 4; ++ks2) {
        step(2 * ks2,     b0, b1, bfA, bfB, true);
        step(2 * ks2 + 1, b1, b0, bfB, bfA, 2 * ks2 + 1 < 7);
    }

    // epilogue: lane (q,ln) of tile (mt,nt) holds p = p0+mw+mt*16+q*4..+3, c = c0+nw+nt*16+ln.
    // 16-deep batched x loads, then add + nontemporal store.
    size_t ebase = ((size_t)n * CD + c0 + nw + ln) * PD + (size_t)(p0 + mw + q * 4);
    f32x4 xv[4][4];
#pragma unroll
    for (int mt = 0; mt < 4; ++mt)
#pragma unroll
        for (int nt = 0; nt < 4; ++nt)
            xv[mt][nt] = *(const f32x4*)(x + ebase + (size_t)nt * 16 * PD + mt * 16);
#pragma unroll
    for (int mt = 0; mt < 4; ++mt)
#pragma unroll
        for (int nt = 0; nt < 4; ++nt) {
            f32x4 r = acc[mt][nt] + xv[mt][nt];
            __builtin_nontemporal_store(r, (f32x4*)(out + ebase + (size_t)nt * 16 * PD + mt * 16));
        }
}

extern "C" void kernel_launch(void* const* d_in, const int* in_sizes, int n_in,
                              void* d_out, int out_size, void* d_ws, size_t ws_size,
                              hipStream_t stream) {
    const float* x     = (const float*)d_in[0];
    const float* w_g   = (const float*)d_in[1];
    const float* b_g   = (const float*)d_in[2];
    const float* w_phi = (const float*)d_in[3];
    const float* b_phi = (const float*)d_in[4];
    float* out = (float*)d_out;

    char* ws = (char*)d_ws;
    _Float16* xT    = (_Float16*)(ws + OFF_XT);
    _Float16* Wc    = (_Float16*)(ws + OFF_WC);
    _Float16* theta = (_Float16*)(ws + OFF_THETA);
    _Float16* gT    = (_Float16*)(ws + OFF_GT);
    _Float16* phi   = (_Float16*)(ws + OFF_PHI);
    _Float16* attn  = (_Float16*)(ws + OFF_ATTN);

    k_prep_w<<<dim3(256), 256, 0, stream>>>(w_g, w_phi, Wc);
    k_prep_x<<<dim3(32, 16, 32), 256, 0, stream>>>(x, xT, theta);
    k_gemm1<<<dim3(32, 4, 32), 256, 0, stream>>>(Wc, xT, b_g, b_phi, gT, phi);
    k_gemm2<<<dim3(32, 32), 256, 0, stream>>>(theta, phi, attn);
    k_gemm3<<<dim3(32, 4, 32), 256, 0, stream>>>(attn, gT, x, out);
}

// Round 6
// 748.479 us; speedup vs baseline: 1.2567x; 1.0187x over previous
//
#include <hip/hip_runtime.h>

// SelfAttentionBlock channel-attention, MI355X fp16-MFMA pipeline.
// N=32, C=512, A=256, H=W=64 (P=4096 flat spatial, PP=1024 pooled).
// Round 6: prep_x fused into gemm1 (xT eliminated); gemm3 = round-2 K-loop + batched epilogue.

typedef _Float16 half8 __attribute__((ext_vector_type(8)));
typedef _Float16 half4v __attribute__((ext_vector_type(4)));
typedef float f32x4 __attribute__((ext_vector_type(4)));

#define NB 32
#define CD 512
#define AD 256
#define PD 4096
#define PPD 1024

// ---------------- workspace layout (bytes) ----------------
// Wc   : fp16 (512, 512)  rows 0-255 = w_g, 256-511 = w_phi
// theta: fp16 (N, C, PP)
// gT   : fp16 (N, P, A)
// phi  : fp16 (N, A, PP)
// attn : fp16 (N, C, A)
#define OFF_WC    134217728UL
#define OFF_THETA 134742016UL
#define OFF_GT    168296448UL
#define OFF_PHI   235405312UL
#define OFF_ATTN  252182528UL

// global->LDS direct (16B/lane). dest must be linear in lane (wave-uniform base + lane*16).
#define GLOAD16(gp, lp) \
    __builtin_amdgcn_global_load_lds((const __attribute__((address_space(1))) void*)(gp), \
                                     (__attribute__((address_space(3))) void*)(lp), 16, 0, 0)

// XOR-swizzled LDS tile [128 rows][32 halves], chunk = 16B (8 halves), 4 chunks/row.
// physical chunk chP at row holds logical chunk chP ^ ((row>>1)&3)  (involution).
__device__ __forceinline__ int swz_off(int row, int q) {
    return row * 32 + ((q ^ ((row >> 1) & 3)) * 8);
}

// Stage one 128x32 A-tile + 128x32 B-tile into LDS via global_load_lds,
// source pre-swizzled so LDS dest stays linear. LD = row stride (halves).
template <int LD>
__device__ __forceinline__ void stage2(const _Float16* __restrict__ Ab,
                                       const _Float16* __restrict__ Bb,
                                       int k0, _Float16* bufA, _Float16* bufB, int t) {
#pragma unroll
    for (int j = 0; j < 4; ++j) {
        int idx = j * 256 + t;            // 0..1023 chunks (512 A + 512 B)
        int ci = idx & 511;
        int row = ci >> 2, chP = ci & 3;
        int chL = chP ^ ((row >> 1) & 3);
        const _Float16* src = ((idx < 512) ? Ab : Bb) + (size_t)row * LD + k0 + chL * 8;
        _Float16* dst = ((idx < 512) ? bufA : bufB) + ci * 8;
        GLOAD16(src, dst);
    }
}

__global__ __launch_bounds__(256) void k_prep_w(const float* __restrict__ w_g,
                                                const float* __restrict__ w_phi,
                                                _Float16* __restrict__ Wc) {
    int idx4 = blockIdx.x * 256 + threadIdx.x;
    int flat = idx4 * 4;
    const float* src = (flat < AD * CD) ? (w_g + flat) : (w_phi + (flat - AD * CD));
    float4 v = *(const float4*)src;
    half4v h;
    h[0] = (_Float16)v.x; h[1] = (_Float16)v.y; h[2] = (_Float16)v.z; h[3] = (_Float16)v.w;
    *(half4v*)(Wc + flat) = h;
}

// Fused GEMM1: per block (pb, n) compute D[a=512][p=128] = Wc · x  (K = c = 512),
// with in-LDS transpose of the x tile (replaces prep_x / xT), emitting:
//   gT[n][p][a<256]  (+b_g, LDS transpose)
//   phi[n][a-256][m'] (+b_phi, 2x2 pool)
//   theta[n][c][m']   (2x2 pooled x, from the staging tiles)
// 16 waves: wave w -> (wa=w>>1: 64 a-rows, wp=w&1: 64 p-cols). K-loop barrier-free:
// A-frags direct from Wc (512 KB, L2-hot across all 1024 blocks), B-frags from LDS panel.
__global__ __launch_bounds__(1024) void k_gemm1f(const _Float16* __restrict__ Wc,
                                                 const float* __restrict__ x,
                                                 const float* __restrict__ b_g,
                                                 const float* __restrict__ b_phi,
                                                 _Float16* __restrict__ gT,
                                                 _Float16* __restrict__ phi,
                                                 _Float16* __restrict__ theta) {
    // panel [128 p][520] = 66560 halves; tile1 [32 c][136] = 4352 halves; total 141824 B.
    // Epilogue reuses: Tg [128][264] at 0 (33792 halves) + Tp [256][136] at 33792 (34816 halves).
    __shared__ _Float16 smem[70912];
    _Float16* panel = smem;
    _Float16* tile1 = smem + 66560;

    int pb = blockIdx.x, n = blockIdx.y;
    int p0 = pb * 128;
    int t = threadIdx.x;
    int w = t >> 6, l = t & 63;
    int ln = l & 15, q = l >> 4;
    int wa = w >> 1, wp = w & 1;
    int a0w = wa * 64, p0w = wp * 64;

    // ---- stage + transpose: x fp32 [512 c][128 p] -> panel fp16 [128 p][520]; emit theta ----
    for (int s = 0; s < 16; ++s) {
        int c0 = s * 32;
        {
            int cl = t >> 5, ch = t & 31;   // 32 c-rows x 32 p-chunks(4)
            float4 v = *(const float4*)(x + ((size_t)n * CD + c0 + cl) * PD + p0 + ch * 4);
            half4v h;
            h[0] = (_Float16)v.x; h[1] = (_Float16)v.y; h[2] = (_Float16)v.z; h[3] = (_Float16)v.w;
            *(half4v*)&tile1[cl * 136 + ch * 4] = h;
        }
        __syncthreads();
        {
            int pl = t >> 3, co = (t & 7) * 4;   // 128 p-rows x 8 c-quads
            _Float16 vals[4] __attribute__((aligned(8)));
#pragma unroll
            for (int j = 0; j < 4; ++j) vals[j] = tile1[(co + j) * 136 + pl];
            *(uint2*)&panel[pl * 520 + c0 + co] = *(uint2*)&vals[0];
        }
        {
            int cl = t >> 5, u = t & 31;   // theta: 32 c-rows x 32 pooled cols
            float a0 = (float)tile1[cl * 136 + 2 * u];
            float a1 = (float)tile1[cl * 136 + 2 * u + 1];
            float a2 = (float)tile1[cl * 136 + 64 + 2 * u];
            float a3 = (float)tile1[cl * 136 + 64 + 2 * u + 1];
            theta[((size_t)n * CD + c0 + cl) * PPD + pb * 32 + u] =
                (_Float16)fmaxf(fmaxf(a0, a1), fmaxf(a2, a3));
        }
        __syncthreads();
    }

    // ---- K-loop: barrier-free, af direct-global (L2-hot Wc) one step ahead, bf from LDS ----
    const f32x4 vzero = {0.f, 0.f, 0.f, 0.f};
    f32x4 acc[4][4];
#pragma unroll
    for (int i = 0; i < 4; ++i)
#pragma unroll
        for (int j = 0; j < 4; ++j) acc[i][j] = vzero;

    const _Float16* arow = Wc + (size_t)(a0w + ln) * CD + q * 8;
    const _Float16* prow = panel + (p0w + ln) * 520 + q * 8;

    half8 afA[4], afB[4], bf[4];
#pragma unroll
    for (int mt = 0; mt < 4; ++mt) afA[mt] = *(const half8*)(arow + mt * 16 * CD);

#pragma unroll
    for (int ks2 = 0; ks2 < 8; ++ks2) {
        int kA = 2 * ks2, kB = 2 * ks2 + 1;
#pragma unroll
        for (int mt = 0; mt < 4; ++mt) afB[mt] = *(const half8*)(arow + mt * 16 * CD + kB * 32);
#pragma unroll
        for (int nt = 0; nt < 4; ++nt) bf[nt] = *(const half8*)(prow + nt * 16 * 520 + kA * 32);
#pragma unroll
        for (int mt = 0; mt < 4; ++mt)
#pragma unroll
            for (int nt = 0; nt < 4; ++nt)
                acc[mt][nt] = __builtin_amdgcn_mfma_f32_16x16x32_f16(afA[mt], bf[nt], acc[mt][nt], 0, 0, 0);
        if (kB < 15) {
#pragma unroll
            for (int mt = 0; mt < 4; ++mt) afA[mt] = *(const half8*)(arow + mt * 16 * CD + (kB + 1) * 32);
        }
#pragma unroll
        for (int nt = 0; nt < 4; ++nt) bf[nt] = *(const half8*)(prow + nt * 16 * 520 + kB * 32);
#pragma unroll
        for (int mt = 0; mt < 4; ++mt)
#pragma unroll
            for (int nt = 0; nt < 4; ++nt)
                acc[mt][nt] = __builtin_amdgcn_mfma_f32_16x16x32_f16(afB[mt], bf[nt], acc[mt][nt], 0, 0, 0);
    }

    __syncthreads();   // all waves done reading panel before LDS reuse

    // ---- epilogue: bias, transpose/pool, write gT / phi ----
    bool is_g = (wa < 4);
    const float* bias = is_g ? b_g : b_phi;
    int ab0 = a0w - (is_g ? 0 : 256);
    float bv[4][4];
#pragma unroll
    for (int mt = 0; mt < 4; ++mt)
#pragma unroll
        for (int r = 0; r < 4; ++r) bv[mt][r] = bias[ab0 + mt * 16 + q * 4 + r];

    _Float16* Tg = smem;            // [128 p][264 a]
    _Float16* Tp = smem + 33792;    // [256 a2][136 p]
    if (is_g) {
#pragma unroll
        for (int mt = 0; mt < 4; ++mt)
#pragma unroll
            for (int nt = 0; nt < 4; ++nt)
#pragma unroll
                for (int r = 0; r < 4; ++r) {
                    int al = a0w + mt * 16 + q * 4 + r;
                    int pl = p0w + nt * 16 + ln;
                    Tg[pl * 264 + al] = (_Float16)(acc[mt][nt][r] + bv[mt][r]);
                }
    } else {
#pragma unroll
        for (int mt = 0; mt < 4; ++mt)
#pragma unroll
            for (int nt = 0; nt < 4; ++nt)
#pragma unroll
                for (int r = 0; r < 4; ++r) {
                    int al = (a0w - 256) + mt * 16 + q * 4 + r;
                    int pl = p0w + nt * 16 + ln;
                    Tp[al * 136 + pl] = (_Float16)(acc[mt][nt][r] + bv[mt][r]);
                }
    }
    __syncthreads();

    // gT: 128 rows x 256 halves = 4096 b128 chunks, 4 per thread
#pragma unroll
    for (int i = 0; i < 4; ++i) {
        int idx = i * 1024 + t;
        int pl = idx >> 5, ch = idx & 31;
        uint4 v = *(uint4*)&Tg[pl * 264 + ch * 8];
        *(uint4*)(gT + ((size_t)n * PD + p0 + pl) * AD + ch * 8) = v;
    }
    // phi: 256 a-rows, 2x2 pool, 8 outputs/thread
    {
        int al = t >> 2, u0 = (t & 3) * 8;
        _Float16 o[8] __attribute__((aligned(16)));
#pragma unroll
        for (int j = 0; j < 8; ++j) {
            int u = u0 + j;
            float v0 = (float)Tp[al * 136 + 2 * u];
            float v1 = (float)Tp[al * 136 + 2 * u + 1];
            float v2 = (float)Tp[al * 136 + 64 + 2 * u];
            float v3 = (float)Tp[al * 136 + 64 + 2 * u + 1];
            o[j] = (_Float16)fmaxf(fmaxf(v0, v1), fmaxf(v2, v3));
        }
        *(uint4*)(phi + ((size_t)n * AD + al) * PPD + pb * 32 + u0) = *(uint4*)&o[0];
    }
}

// GEMM2 + softmax, K-split across waves for occupancy.
__global__ __launch_bounds__(256) void k_gemm2(const _Float16* __restrict__ theta,
                                               const _Float16* __restrict__ phi,
                                               _Float16* __restrict__ attn) {
    __shared__ float red[3 * 64 * 65];
    int cb = blockIdx.x;   // 0..31
    int n  = blockIdx.y;
    int t = threadIdx.x, w = t >> 6, l = t & 63;
    int ln = l & 15, q = l >> 4;
    int c0 = cb * 16;

    const _Float16* Ab = theta + ((size_t)n * CD + c0 + ln) * PPD + w * 256;
    const _Float16* Bb = phi + ((size_t)n * AD + ln) * PPD + w * 256;

    const f32x4 vzero = {0.f, 0.f, 0.f, 0.f};
    f32x4 acc[16];
#pragma unroll
    for (int i = 0; i < 16; ++i) acc[i] = vzero;

    for (int k0 = 0; k0 < 256; k0 += 32) {
        half8 af = *(const half8*)(Ab + k0 + q * 8);
#pragma unroll
        for (int nt = 0; nt < 16; ++nt) {
            half8 bf = *(const half8*)(Bb + (size_t)nt * 16 * PPD + k0 + q * 8);
            acc[nt] = __builtin_amdgcn_mfma_f32_16x16x32_f16(af, bf, acc[nt], 0, 0, 0);
        }
    }

    if (w > 0) {
        float* dst = red + (w - 1) * 64 * 65 + l * 65;
#pragma unroll
        for (int nt = 0; nt < 16; ++nt)
#pragma unroll
            for (int r = 0; r < 4; ++r) dst[nt * 4 + r] = acc[nt][r];
    }
    __syncthreads();
    if (w == 0) {
#pragma unroll
        for (int j = 0; j < 3; ++j) {
            const float* src = red + j * 64 * 65 + l * 65;
#pragma unroll
            for (int nt = 0; nt < 16; ++nt)
#pragma unroll
                for (int r = 0; r < 4; ++r) acc[nt][r] += src[nt * 4 + r];
        }
#pragma unroll
        for (int r = 0; r < 4; ++r) {
            float m = -1e30f;
#pragma unroll
            for (int nt = 0; nt < 16; ++nt) m = fmaxf(m, acc[nt][r]);
#pragma unroll
            for (int s = 1; s < 16; s <<= 1) m = fmaxf(m, __shfl_xor(m, s, 64));
            float sum = 0.f;
#pragma unroll
            for (int nt = 0; nt < 16; ++nt) {
                float e = __expf(acc[nt][r] - m);
                acc[nt][r] = e;
                sum += e;
            }
#pragma unroll
            for (int s = 1; s < 16; s <<= 1) sum += __shfl_xor(sum, s, 64);
            float inv = 1.0f / sum;
            int c = c0 + q * 4 + r;
            _Float16* dst = attn + ((size_t)n * CD + c) * AD + ln;
#pragma unroll
            for (int nt = 0; nt < 16; ++nt) dst[nt * 16] = (_Float16)(acc[nt][r] * inv);
        }
    }
}

// GEMM3: out[c][p] = sum_a attn[c][a] * gT[p][a] + x[c][p].  128x128 tile, K=256.
// Round-2 K-loop (2-buf global_load_lds, swizzled, best measured) + batched epilogue.
__global__ __launch_bounds__(256) void k_gemm3(const _Float16* __restrict__ attn,
                                               const _Float16* __restrict__ gT,
                                               const float* __restrict__ x,
                                               float* __restrict__ out) {
    __shared__ _Float16 smem[16384];   // 2 bufs x (As 4096 + Bs 4096)

    int pb = blockIdx.x, cb = blockIdx.y, n = blockIdx.z;
    int c0 = cb * 128, p0 = pb * 128;
    int t = threadIdx.x;
    int w = t >> 6, l = t & 63;
    int ln = l & 15, q = l >> 4;
    int mw = (w >> 1) * 64, nw = (w & 1) * 64;   // mw: p-tile, nw: c-tile

    const f32x4 vzero = {0.f, 0.f, 0.f, 0.f};
    f32x4 acc[4][4];
#pragma unroll
    for (int i = 0; i < 4; ++i)
#pragma unroll
        for (int j = 0; j < 4; ++j) acc[i][j] = vzero;

    const _Float16* Abase = attn + ((size_t)n * CD + c0) * AD;   // 128 c rows
    const _Float16* Bbase = gT + ((size_t)n * PD + p0) * AD;     // 128 p rows

    stage2<AD>(Abase, Bbase, 0, smem, smem + 4096, t);
    __syncthreads();

    for (int ks = 0; ks < 8; ++ks) {
        int oc = (ks & 1) << 13;
        int on = oc ^ 8192;
        if (ks < 7) stage2<AD>(Abase, Bbase, (ks + 1) * 32, smem + on, smem + on + 4096, t);
        _Float16* As = smem + oc;          // attn tile (c rows)
        _Float16* Bs = smem + oc + 4096;   // gT tile (p rows)
        half8 af[4], bf[4];
        // A-operand = gT rows (p) -> D rows = p; B-operand = attn rows (c) -> D cols = c
#pragma unroll
        for (int mt = 0; mt < 4; ++mt) af[mt] = *(const half8*)&Bs[swz_off(mw + mt * 16 + ln, q)];
#pragma unroll
        for (int nt = 0; nt < 4; ++nt) bf[nt] = *(const half8*)&As[swz_off(nw + nt * 16 + ln, q)];
#pragma unroll
        for (int mt = 0; mt < 4; ++mt)
#pragma unroll
            for (int nt = 0; nt < 4; ++nt)
                acc[mt][nt] = __builtin_amdgcn_mfma_f32_16x16x32_f16(af[mt], bf[nt], acc[mt][nt], 0, 0, 0);
        __syncthreads();
    }

    // epilogue: lane (q,ln) of tile (mt,nt) holds p = p0+mw+mt*16+q*4..+3, c = c0+nw+nt*16+ln.
    // 16-deep batched x loads (MLP), then add + nontemporal store.
    size_t ebase = ((size_t)n * CD + c0 + nw + ln) * PD + (size_t)(p0 + mw + q * 4);
    f32x4 xv[4][4];
#pragma unroll
    for (int mt = 0; mt < 4; ++mt)
#pragma unroll
        for (int nt = 0; nt < 4; ++nt)
            xv[mt][nt] = *(const f32x4*)(x + ebase + (size_t)nt * 16 * PD + mt * 16);
#pragma unroll
    for (int mt = 0; mt < 4; ++mt)
#pragma unroll
        for (int nt = 0; nt < 4; ++nt) {
            f32x4 r = acc[mt][nt] + xv[mt][nt];
            __builtin_nontemporal_store(r, (f32x4*)(out + ebase + (size_t)nt * 16 * PD + mt * 16));
        }
}

extern "C" void kernel_launch(void* const* d_in, const int* in_sizes, int n_in,
                              void* d_out, int out_size, void* d_ws, size_t ws_size,
                              hipStream_t stream) {
    const float* x     = (const float*)d_in[0];
    const float* w_g   = (const float*)d_in[1];
    const float* b_g   = (const float*)d_in[2];
    const float* w_phi = (const float*)d_in[3];
    const float* b_phi = (const float*)d_in[4];
    float* out = (float*)d_out;

    char* ws = (char*)d_ws;
    _Float16* Wc    = (_Float16*)(ws + OFF_WC);
    _Float16* theta = (_Float16*)(ws + OFF_THETA);
    _Float16* gT    = (_Float16*)(ws + OFF_GT);
    _Float16* phi   = (_Float16*)(ws + OFF_PHI);
    _Float16* attn  = (_Float16*)(ws + OFF_ATTN);

    k_prep_w<<<dim3(256), 256, 0, stream>>>(w_g, w_phi, Wc);
    k_gemm1f<<<dim3(32, 32), 1024, 0, stream>>>(Wc, x, b_g, b_phi, gT, phi, theta);
    k_gemm2<<<dim3(32, 32), 256, 0, stream>>>(theta, phi, attn);
    k_gemm3<<<dim3(32, 4, 32), 256, 0, stream>>>(attn, gT, x, out);
}